// Round 31
// baseline (112.436 us; speedup 1.0000x reference)
//
#include <hip/hip_runtime.h>
#include <hip/hip_bf16.h>
#include <hip/hip_fp16.h>
#include <cstdint>

typedef __attribute__((ext_vector_type(8))) short s16x8;
typedef __attribute__((ext_vector_type(8))) _Float16 f16x8;
typedef __attribute__((ext_vector_type(4))) float f32x4;

__device__ __forceinline__ void gload16(const void* g, void* l){
  __builtin_amdgcn_global_load_lds((const __attribute__((address_space(1))) void*)g,
                                   (__attribute__((address_space(3))) void*)l, 16, 0, 0);
}

// transpose + convert: in[K][N] f32 -> outT[N][K] fp16
__global__ void transpose_f16(const float* __restrict__ in, ushort* __restrict__ outT,
                              int K, int N){
  __shared__ float tile[32][33];
  const int kb = blockIdx.y * 32, nb = blockIdx.x * 32;
  const int tx = threadIdx.x & 31, ty = threadIdx.x >> 5;  // ty: 0..7
#pragma unroll
  for (int r = 0; r < 32; r += 8)
    tile[ty + r][tx] = in[(size_t)(kb + ty + r) * N + nb + tx];
  __syncthreads();
#pragma unroll
  for (int r = 0; r < 32; r += 8){
    const float v = tile[tx][ty + r];
    const _Float16 h = (_Float16)v;
    outT[(size_t)(nb + ty + r) * K + kb + tx] = __builtin_bit_cast(ushort, h);
  }
}

// out[m][c] = b3[c] + part[0][m][c] + part[1][m][c]
__global__ void finish_out(const float* __restrict__ part, const float* __restrict__ b3,
                           float* __restrict__ out){
  const int idx = blockIdx.x * 256 + threadIdx.x;   // 327680 = 32768*10
  if (idx >= 32768 * 10) return;
  out[idx] = b3[idx % 10] + part[idx] + part[327680 + idx];
}

// ---- 128x256-tile fp16 GEMM (final: R17 structure + T14 async A-stage) -------
// A: M x K row-major (MODE 0: f32 source, reg-staged fused convert with
// next-tile loads issued under current tile's MFMA phase; MODE 1: fp16 via
// global_load_lds).  B: N x K fp16 row-major (pre-transposed weights).
// 4 waves (1M x 4N), per-wave 128x64 output (acc 8x4 f32x4), 2 blocks/CU.
// Register budget: gfx950 unified VGPR/AGPR file; 120 VGPR + 128 AGPR = 248
// of the 256/wave cap from (256,2). Registers (not LDS) bind occupancy at
// 8 waves/CU for ANY BK at this acc size.
// Session A/B ledger: B-dbuf spills [R21/R25]; 8-wave halves compute/barrier
// [R23]; 3-block occupancy infeasible [R13/R18]; counted publish null [R27];
// setprio removal regresses ~2us [R29] -> setprio kept. Verified fixed point:
// 111.7-112.9 us over 7 runs, absmax 1.953e-3.
// LDS: main loop A[128][64] hw 0..8191, B[256][64] hw 8192..24575 (XOR-swizzled
// rows); epilogue act-tile [128][256] hw 0..32767.
// MODE 0: blend_act -> fp16 h1 store.
// MODE 1: relu -> act tile stays in LDS; epilogue contracts it with a [16][264]
//         fp16 W3 pane via 16 MFMA/wave -> deterministic partials (no h2 HBM).
template<int MODE>
__global__ __launch_bounds__(256, 2)
void gemm_f16_128x256(const void* __restrict__ Asrc, const ushort* __restrict__ Bw,
                      const float* __restrict__ bias, ushort* __restrict__ outH,
                      const float* __restrict__ W3, float* __restrict__ part,
                      int N, int K)
{
  __shared__ ushort lds[MODE == 0 ? 32768 : 36992];  // MODE1: +[16][264] W3 pane
  const int t = threadIdx.x;
  const int lane = t & 63;
  const int wn = t >> 6;                   // wave grid 1(M) x 4(N)
  const int ln15 = lane & 15, lnHi = lane >> 4;

  // XCD-aware bijective swizzle (nwg divisible by 8)
  const int gx = gridDim.x;
  const int nwg = gx * gridDim.y;
  const int bid = blockIdx.y * gx + blockIdx.x;
  const int swz = (bid & 7) * (nwg >> 3) + (bid >> 3);
  const int m0 = (swz / gx) * 128;
  const int n0 = (swz % gx) * 256;

  const ushort* gB = Bw + (size_t)n0 * K;

  if constexpr (MODE == 1){
    // stage W3 pane: w3lds[c][k] = c<10 ? fp16(W3[(n0+k)*10+c]) : 0
    ushort* w3lds = &lds[32768];
#pragma unroll
    for (int i2 = 0; i2 < 16; ++i2){
      const int idx = i2 * 256 + t;
      const int c = idx >> 8, k = idx & 255;
      const float v = (c < 10) ? W3[(size_t)(n0 + k) * 10 + c] : 0.f;
      w3lds[c * 264 + k] = __builtin_bit_cast(ushort, (_Float16)v);
    }
  }

  // -------- staging constants --------
  const int rh0  = t >> 3;                                 // base row (0..31)
  const int slot = t & 7;
  const int gkhw = ((slot << 4) ^ ((rh0 & 7) << 4)) >> 1;  // inv-swizzled k (hw)
  const uint dA = (uint)(rh0 * 64 + slot * 8);             // + c*2048 per 32 rows
  const uint dB = (uint)(8192 + rh0 * 64 + slot * 8);
  const ushort* pB = gB + (size_t)rh0 * K + gkhw;
  // MODE 0: natural-k f32 source + swizzled ds_write slot
  const float*  pAf = (const float*)Asrc + ((size_t)(m0 + rh0)) * K + slot * 8;
  const uint    dAw = (uint)(rh0 * 64 + ((slot ^ (rh0 & 7)) << 3));
  // MODE 1: inverse-swizzled fp16 source + linear gload dest
  const ushort* pAh = (const ushort*)Asrc + ((size_t)(m0 + rh0)) * K + gkhw;

  // -------- fragment-read bases (hw; XOR swizzle baked in) --------
  const int swb = (ln15 & 7) << 4;                         // bytes, bits 4-6
  const int koff0 = ((lnHi * 16) ^ swb) >> 1;
  const int koff1 = koff0 ^ 32;                            // +64B (lnHi*16 < 64)
  const int hA = ln15 * 64;                                // + m*1024 + koff
  const int hB = 8192 + (wn * 64 + ln15) * 64;             // + j*1024 + koff

  f32x4 acc[8][4] = {};

  auto loadA = [&](f32x4 (&av)[4][2], int kt){
#pragma unroll
    for (int c = 0; c < 4; ++c){
      const float* src = pAf + (size_t)c * 32 * K + kt;
      av[c][0] = *(const f32x4*)src;
      av[c][1] = *(const f32x4*)(src + 4);
    }
  };
  auto writeA = [&](const f32x4 (&av)[4][2]){
#pragma unroll
    for (int c = 0; c < 4; ++c){
      f16x8 hv;
#pragma unroll
      for (int j = 0; j < 4; ++j){
        hv[j]     = (_Float16)av[c][0][j];
        hv[4 + j] = (_Float16)av[c][1][j];
      }
      *(f16x8*)&lds[dAw + c * 2048] = hv;
    }
  };
  auto stageB = [&](int kt){
#pragma unroll
    for (int c = 0; c < 8; ++c)
      gload16(pB + (size_t)c * 32 * K + kt, &lds[dB + c * 2048]);
  };
  auto mfmaTile = [&](){
    {
      f16x8 af[8], bfv[4];
#pragma unroll
      for (int m = 0; m < 8; ++m)
        af[m] = *(const f16x8*)&lds[hA + m * 1024 + koff0];
#pragma unroll
      for (int j = 0; j < 4; ++j)
        bfv[j] = *(const f16x8*)&lds[hB + j * 1024 + koff0];
      __builtin_amdgcn_s_setprio(1);
#pragma unroll
      for (int m = 0; m < 8; ++m)
#pragma unroll
        for (int j = 0; j < 4; ++j)
          acc[m][j] = __builtin_amdgcn_mfma_f32_16x16x32_f16(af[m], bfv[j], acc[m][j], 0, 0, 0);
      __builtin_amdgcn_s_setprio(0);
    }
    __builtin_amdgcn_sched_barrier(0);     // cap fragment liveness
    {
      f16x8 af[8], bfv[4];
#pragma unroll
      for (int m = 0; m < 8; ++m)
        af[m] = *(const f16x8*)&lds[hA + m * 1024 + koff1];
#pragma unroll
      for (int j = 0; j < 4; ++j)
        bfv[j] = *(const f16x8*)&lds[hB + j * 1024 + koff1];
      __builtin_amdgcn_s_setprio(1);
#pragma unroll
      for (int m = 0; m < 8; ++m)
#pragma unroll
        for (int j = 0; j < 4; ++j)
          acc[m][j] = __builtin_amdgcn_mfma_f32_16x16x32_f16(af[m], bfv[j], acc[m][j], 0, 0, 0);
      __builtin_amdgcn_s_setprio(0);
    }
  };

  if constexpr (MODE == 0){
    // T14 async-STAGE: next tile's A-loads issue under current tile's MFMA.
    // K/64 is even (K=512): unroll by 2 with two register sets (static idx).
    f32x4 avA[4][2], avB[4][2];
    loadA(avA, 0);
    for (int kt = 0; kt < K; kt += 128){
      __syncthreads();                     // WAR
      stageB(kt);
      writeA(avA);
      loadA(avB, kt + 64);                 // in flight across publish barrier
      __syncthreads();                     // publish
      mfmaTile();
      __syncthreads();                     // WAR
      stageB(kt + 64);
      writeA(avB);
      loadA(avA, (kt + 128 < K) ? kt + 128 : 0);  // wrap: dead on last iter
      __syncthreads();                     // publish
      mfmaTile();
    }
  } else {
    for (int kt = 0; kt < K; kt += 64){
      __syncthreads();                     // WAR
#pragma unroll
      for (int c = 0; c < 4; ++c)
        gload16(pAh + (size_t)c * 32 * K + kt, &lds[dA + c * 2048]);
      stageB(kt);
      __syncthreads();                     // publish
      mfmaTile();
    }
  }

  __syncthreads();  // all main-loop LDS reads done before epilogue overwrite

  // ---- epilogue part 1: act -> fp16 -> LDS [128][256] (XOR swizzle) ----
  const int rowbase = lnHi * 4;
  const int colbase = wn * 64 + ln15;
#pragma unroll
  for (int j = 0; j < 4; ++j){
    const int col = colbase + j * 16;
    const float bv = bias[n0 + col];
#pragma unroll
    for (int i = 0; i < 8; ++i){
#pragma unroll
      for (int r = 0; r < 4; ++r){
        const int row = rowbase + i * 16 + r;
        const float v = acc[i][j][r] + bv;
        float a;
        if (MODE == 0){
          const float th = 1.f - 2.f / (__expf(2.f * v) + 1.f);  // tanh(v)
          a = v > 0.f ? v * 0.9f + th * 0.1f : th * 0.5f;
        } else {
          a = v > 0.f ? v : 0.f;
        }
        const _Float16 h = (_Float16)a;
        lds[row * 256 + (col ^ ((row & 7) << 3))] = __builtin_bit_cast(ushort, h);
      }
    }
  }
  __syncthreads();

  if constexpr (MODE == 0){
    // coalesced h1 store
#pragma unroll
    for (int it = 0; it < 16; ++it){
      const int chunk = it * 256 + t;          // 128 rows x 32 chunks of 8 hw
      const int row = chunk >> 5, g = chunk & 31;
      const s16x8 vv = *(const s16x8*)&lds[row * 256 + ((g ^ (row & 7)) << 3)];
      *(s16x8*)&outH[(size_t)(m0 + row) * N + n0 + (g << 3)] = vv;
    }
  } else {
    // ---- epilogue part 2: fused GEMM3 partial via MFMA ----
    // part[nb][m][c] = sum_{k<256} h2tile[m][k] * W3[n0+k][c]
    const ushort* w3lds = &lds[32768];
    const int nb = n0 >> 8;                    // 0 or 1
    f32x4 p3[2] = {};
#pragma unroll
    for (int ks = 0; ks < 8; ++ks){
      const f16x8 bw = *(const f16x8*)&w3lds[ln15 * 264 + ks * 32 + lnHi * 8];
#pragma unroll
      for (int f = 0; f < 2; ++f){
        const int mr = wn * 32 + f * 16 + ln15;
        const int colhw = ks * 32 + lnHi * 8;
        const f16x8 aw = *(const f16x8*)&lds[mr * 256 + (colhw ^ ((mr & 7) << 3))];
        p3[f] = __builtin_amdgcn_mfma_f32_16x16x32_f16(aw, bw, p3[f], 0, 0, 0);
      }
    }
    const int c = ln15;                        // C-frag: col = lane&15
    if (c < 10){
#pragma unroll
      for (int f = 0; f < 2; ++f)
#pragma unroll
        for (int r = 0; r < 4; ++r){
          const int m = m0 + wn * 32 + f * 16 + lnHi * 4 + r;
          part[((size_t)nb * 32768 + m) * 10 + c] = p3[f][r];
        }
    }
  }
}

extern "C" void kernel_launch(void* const* d_in, const int* in_sizes, int n_in,
                              void* d_out, int out_size, void* d_ws, size_t ws_size,
                              hipStream_t stream){
  const float* x  = (const float*)d_in[0];
  const float* W1 = (const float*)d_in[1];
  const float* b1 = (const float*)d_in[2];
  const float* W2 = (const float*)d_in[3];
  const float* b2 = (const float*)d_in[4];
  const float* W3 = (const float*)d_in[5];
  const float* b3 = (const float*)d_in[6];
  float* out = (float*)d_out;

  const int B = 32768, Din = 512, H = 1024, Hh = 512;
  char* ws = (char*)d_ws;
  const size_t MB = (size_t)1 << 20;
  // ws layout (~98 MB):
  ushort* h1   = (ushort*)(ws);            // 64 MB  (32768 x 1024 fp16)
  float*  part = (float*)(ws + 64 * MB);   // 2.62 MB (2 x 32768 x 10 f32)
  ushort* W1T  = (ushort*)(ws + 96 * MB);  // 1 MB   (1024 x 512 fp16)
  ushort* W2T  = (ushort*)(ws + 97 * MB);  // 1 MB   (512 x 1024 fp16)

  transpose_f16<<<dim3(H / 32, Din / 32), 256, 0, stream>>>(W1, W1T, Din, H);
  transpose_f16<<<dim3(Hh / 32, H / 32), 256, 0, stream>>>(W2, W2T, H, Hh);

  gemm_f16_128x256<0><<<dim3(H / 256, B / 128), 256, 0, stream>>>(
      x,  W1T, b1, h1, nullptr, nullptr, H, Din);
  gemm_f16_128x256<1><<<dim3(Hh / 256, B / 128), 256, 0, stream>>>(
      h1, W2T, b2, nullptr, W3, part, Hh, H);
  finish_out<<<(B * 10 + 255) / 256, 256, 0, stream>>>(part, b3, out);
}

// Round 32
// 111.737 us; speedup vs baseline: 1.0063x; 1.0063x over previous
//
#include <hip/hip_runtime.h>
#include <hip/hip_bf16.h>
#include <hip/hip_fp16.h>
#include <cstdint>

typedef __attribute__((ext_vector_type(8))) short s16x8;
typedef __attribute__((ext_vector_type(8))) _Float16 f16x8;
typedef __attribute__((ext_vector_type(4))) float f32x4;

__device__ __forceinline__ void gload16(const void* g, void* l){
  __builtin_amdgcn_global_load_lds((const __attribute__((address_space(1))) void*)g,
                                   (__attribute__((address_space(3))) void*)l, 16, 0, 0);
}

// transpose + convert: in[K][N] f32 -> outT[N][K] fp16
__global__ void transpose_f16(const float* __restrict__ in, ushort* __restrict__ outT,
                              int K, int N){
  __shared__ float tile[32][33];
  const int kb = blockIdx.y * 32, nb = blockIdx.x * 32;
  const int tx = threadIdx.x & 31, ty = threadIdx.x >> 5;  // ty: 0..7
#pragma unroll
  for (int r = 0; r < 32; r += 8)
    tile[ty + r][tx] = in[(size_t)(kb + ty + r) * N + nb + tx];
  __syncthreads();
#pragma unroll
  for (int r = 0; r < 32; r += 8){
    const float v = tile[tx][ty + r];
    const _Float16 h = (_Float16)v;
    outT[(size_t)(nb + ty + r) * K + kb + tx] = __builtin_bit_cast(ushort, h);
  }
}

// out[m][c] = b3[c] + part[0][m][c] + part[1][m][c]
__global__ void finish_out(const float* __restrict__ part, const float* __restrict__ b3,
                           float* __restrict__ out){
  const int idx = blockIdx.x * 256 + threadIdx.x;   // 327680 = 32768*10
  if (idx >= 32768 * 10) return;
  out[idx] = b3[idx % 10] + part[idx] + part[327680 + idx];
}

// ---- 128x256-tile fp16 GEMM (final: R17 structure + T14 async A-stage) -------
// A: M x K row-major (MODE 0: f32 source, reg-staged fused convert with
// next-tile loads issued under current tile's MFMA phase; MODE 1: fp16 via
// global_load_lds).  B: N x K fp16 row-major (pre-transposed weights).
// 4 waves (1M x 4N), per-wave 128x64 output (acc 8x4 f32x4), 2 blocks/CU.
// Register budget: gfx950 unified VGPR/AGPR file; 120 VGPR + 128 AGPR = 248
// of the 256/wave cap from (256,2). Registers (not LDS) bind occupancy at
// 8 waves/CU for ANY BK at this acc size.
// Session A/B ledger: B-dbuf spills [R21/R25]; 8-wave halves compute/barrier
// [R23]; 3-block occupancy infeasible [R13/R18]; counted publish null [R27];
// setprio removal regresses ~2us [R29] -> setprio kept. Verified fixed point:
// 111.7-112.9 us over 8 runs, absmax 1.953e-3.
// LDS: main loop A[128][64] hw 0..8191, B[256][64] hw 8192..24575 (XOR-swizzled
// rows); epilogue act-tile [128][256] hw 0..32767.
// MODE 0: blend_act -> fp16 h1 store.
// MODE 1: relu -> act tile stays in LDS; epilogue contracts it with a [16][264]
//         fp16 W3 pane via 16 MFMA/wave -> deterministic partials (no h2 HBM).
template<int MODE>
__global__ __launch_bounds__(256, 2)
void gemm_f16_128x256(const void* __restrict__ Asrc, const ushort* __restrict__ Bw,
                      const float* __restrict__ bias, ushort* __restrict__ outH,
                      const float* __restrict__ W3, float* __restrict__ part,
                      int N, int K)
{
  __shared__ ushort lds[MODE == 0 ? 32768 : 36992];  // MODE1: +[16][264] W3 pane
  const int t = threadIdx.x;
  const int lane = t & 63;
  const int wn = t >> 6;                   // wave grid 1(M) x 4(N)
  const int ln15 = lane & 15, lnHi = lane >> 4;

  // XCD-aware bijective swizzle (nwg divisible by 8)
  const int gx = gridDim.x;
  const int nwg = gx * gridDim.y;
  const int bid = blockIdx.y * gx + blockIdx.x;
  const int swz = (bid & 7) * (nwg >> 3) + (bid >> 3);
  const int m0 = (swz / gx) * 128;
  const int n0 = (swz % gx) * 256;

  const ushort* gB = Bw + (size_t)n0 * K;

  if constexpr (MODE == 1){
    // stage W3 pane: w3lds[c][k] = c<10 ? fp16(W3[(n0+k)*10+c]) : 0
    ushort* w3lds = &lds[32768];
#pragma unroll
    for (int i2 = 0; i2 < 16; ++i2){
      const int idx = i2 * 256 + t;
      const int c = idx >> 8, k = idx & 255;
      const float v = (c < 10) ? W3[(size_t)(n0 + k) * 10 + c] : 0.f;
      w3lds[c * 264 + k] = __builtin_bit_cast(ushort, (_Float16)v);
    }
  }

  // -------- staging constants --------
  const int rh0  = t >> 3;                                 // base row (0..31)
  const int slot = t & 7;
  const int gkhw = ((slot << 4) ^ ((rh0 & 7) << 4)) >> 1;  // inv-swizzled k (hw)
  const uint dA = (uint)(rh0 * 64 + slot * 8);             // + c*2048 per 32 rows
  const uint dB = (uint)(8192 + rh0 * 64 + slot * 8);
  const ushort* pB = gB + (size_t)rh0 * K + gkhw;
  // MODE 0: natural-k f32 source + swizzled ds_write slot
  const float*  pAf = (const float*)Asrc + ((size_t)(m0 + rh0)) * K + slot * 8;
  const uint    dAw = (uint)(rh0 * 64 + ((slot ^ (rh0 & 7)) << 3));
  // MODE 1: inverse-swizzled fp16 source + linear gload dest
  const ushort* pAh = (const ushort*)Asrc + ((size_t)(m0 + rh0)) * K + gkhw;

  // -------- fragment-read bases (hw; XOR swizzle baked in) --------
  const int swb = (ln15 & 7) << 4;                         // bytes, bits 4-6
  const int koff0 = ((lnHi * 16) ^ swb) >> 1;
  const int koff1 = koff0 ^ 32;                            // +64B (lnHi*16 < 64)
  const int hA = ln15 * 64;                                // + m*1024 + koff
  const int hB = 8192 + (wn * 64 + ln15) * 64;             // + j*1024 + koff

  f32x4 acc[8][4] = {};

  auto loadA = [&](f32x4 (&av)[4][2], int kt){
#pragma unroll
    for (int c = 0; c < 4; ++c){
      const float* src = pAf + (size_t)c * 32 * K + kt;
      av[c][0] = *(const f32x4*)src;
      av[c][1] = *(const f32x4*)(src + 4);
    }
  };
  auto writeA = [&](const f32x4 (&av)[4][2]){
#pragma unroll
    for (int c = 0; c < 4; ++c){
      f16x8 hv;
#pragma unroll
      for (int j = 0; j < 4; ++j){
        hv[j]     = (_Float16)av[c][0][j];
        hv[4 + j] = (_Float16)av[c][1][j];
      }
      *(f16x8*)&lds[dAw + c * 2048] = hv;
    }
  };
  auto stageB = [&](int kt){
#pragma unroll
    for (int c = 0; c < 8; ++c)
      gload16(pB + (size_t)c * 32 * K + kt, &lds[dB + c * 2048]);
  };
  auto mfmaTile = [&](){
    {
      f16x8 af[8], bfv[4];
#pragma unroll
      for (int m = 0; m < 8; ++m)
        af[m] = *(const f16x8*)&lds[hA + m * 1024 + koff0];
#pragma unroll
      for (int j = 0; j < 4; ++j)
        bfv[j] = *(const f16x8*)&lds[hB + j * 1024 + koff0];
      __builtin_amdgcn_s_setprio(1);
#pragma unroll
      for (int m = 0; m < 8; ++m)
#pragma unroll
        for (int j = 0; j < 4; ++j)
          acc[m][j] = __builtin_amdgcn_mfma_f32_16x16x32_f16(af[m], bfv[j], acc[m][j], 0, 0, 0);
      __builtin_amdgcn_s_setprio(0);
    }
    __builtin_amdgcn_sched_barrier(0);     // cap fragment liveness
    {
      f16x8 af[8], bfv[4];
#pragma unroll
      for (int m = 0; m < 8; ++m)
        af[m] = *(const f16x8*)&lds[hA + m * 1024 + koff1];
#pragma unroll
      for (int j = 0; j < 4; ++j)
        bfv[j] = *(const f16x8*)&lds[hB + j * 1024 + koff1];
      __builtin_amdgcn_s_setprio(1);
#pragma unroll
      for (int m = 0; m < 8; ++m)
#pragma unroll
        for (int j = 0; j < 4; ++j)
          acc[m][j] = __builtin_amdgcn_mfma_f32_16x16x32_f16(af[m], bfv[j], acc[m][j], 0, 0, 0);
      __builtin_amdgcn_s_setprio(0);
    }
  };

  if constexpr (MODE == 0){
    // T14 async-STAGE: next tile's A-loads issue under current tile's MFMA.
    // K/64 is even (K=512): unroll by 2 with two register sets (static idx).
    f32x4 avA[4][2], avB[4][2];
    loadA(avA, 0);
    for (int kt = 0; kt < K; kt += 128){
      __syncthreads();                     // WAR
      stageB(kt);
      writeA(avA);
      loadA(avB, kt + 64);                 // in flight across publish barrier
      __syncthreads();                     // publish
      mfmaTile();
      __syncthreads();                     // WAR
      stageB(kt + 64);
      writeA(avB);
      loadA(avA, (kt + 128 < K) ? kt + 128 : 0);  // wrap: dead on last iter
      __syncthreads();                     // publish
      mfmaTile();
    }
  } else {
    for (int kt = 0; kt < K; kt += 64){
      __syncthreads();                     // WAR
#pragma unroll
      for (int c = 0; c < 4; ++c)
        gload16(pAh + (size_t)c * 32 * K + kt, &lds[dA + c * 2048]);
      stageB(kt);
      __syncthreads();                     // publish
      mfmaTile();
    }
  }

  __syncthreads();  // all main-loop LDS reads done before epilogue overwrite

  // ---- epilogue part 1: act -> fp16 -> LDS [128][256] (XOR swizzle) ----
  const int rowbase = lnHi * 4;
  const int colbase = wn * 64 + ln15;
#pragma unroll
  for (int j = 0; j < 4; ++j){
    const int col = colbase + j * 16;
    const float bv = bias[n0 + col];
#pragma unroll
    for (int i = 0; i < 8; ++i){
#pragma unroll
      for (int r = 0; r < 4; ++r){
        const int row = rowbase + i * 16 + r;
        const float v = acc[i][j][r] + bv;
        float a;
        if (MODE == 0){
          const float th = 1.f - 2.f / (__expf(2.f * v) + 1.f);  // tanh(v)
          a = v > 0.f ? v * 0.9f + th * 0.1f : th * 0.5f;
        } else {
          a = v > 0.f ? v : 0.f;
        }
        const _Float16 h = (_Float16)a;
        lds[row * 256 + (col ^ ((row & 7) << 3))] = __builtin_bit_cast(ushort, h);
      }
    }
  }
  __syncthreads();

  if constexpr (MODE == 0){
    // coalesced h1 store
#pragma unroll
    for (int it = 0; it < 16; ++it){
      const int chunk = it * 256 + t;          // 128 rows x 32 chunks of 8 hw
      const int row = chunk >> 5, g = chunk & 31;
      const s16x8 vv = *(const s16x8*)&lds[row * 256 + ((g ^ (row & 7)) << 3)];
      *(s16x8*)&outH[(size_t)(m0 + row) * N + n0 + (g << 3)] = vv;
    }
  } else {
    // ---- epilogue part 2: fused GEMM3 partial via MFMA ----
    // part[nb][m][c] = sum_{k<256} h2tile[m][k] * W3[n0+k][c]
    const ushort* w3lds = &lds[32768];
    const int nb = n0 >> 8;                    // 0 or 1
    f32x4 p3[2] = {};
#pragma unroll
    for (int ks = 0; ks < 8; ++ks){
      const f16x8 bw = *(const f16x8*)&w3lds[ln15 * 264 + ks * 32 + lnHi * 8];
#pragma unroll
      for (int f = 0; f < 2; ++f){
        const int mr = wn * 32 + f * 16 + ln15;
        const int colhw = ks * 32 + lnHi * 8;
        const f16x8 aw = *(const f16x8*)&lds[mr * 256 + (colhw ^ ((mr & 7) << 3))];
        p3[f] = __builtin_amdgcn_mfma_f32_16x16x32_f16(aw, bw, p3[f], 0, 0, 0);
      }
    }
    const int c = ln15;                        // C-frag: col = lane&15
    if (c < 10){
#pragma unroll
      for (int f = 0; f < 2; ++f)
#pragma unroll
        for (int r = 0; r < 4; ++r){
          const int m = m0 + wn * 32 + f * 16 + lnHi * 4 + r;
          part[((size_t)nb * 32768 + m) * 10 + c] = p3[f][r];
        }
    }
  }
}

extern "C" void kernel_launch(void* const* d_in, const int* in_sizes, int n_in,
                              void* d_out, int out_size, void* d_ws, size_t ws_size,
                              hipStream_t stream){
  const float* x  = (const float*)d_in[0];
  const float* W1 = (const float*)d_in[1];
  const float* b1 = (const float*)d_in[2];
  const float* W2 = (const float*)d_in[3];
  const float* b2 = (const float*)d_in[4];
  const float* W3 = (const float*)d_in[5];
  const float* b3 = (const float*)d_in[6];
  float* out = (float*)d_out;

  const int B = 32768, Din = 512, H = 1024, Hh = 512;
  char* ws = (char*)d_ws;
  const size_t MB = (size_t)1 << 20;
  // ws layout (~98 MB):
  ushort* h1   = (ushort*)(ws);            // 64 MB  (32768 x 1024 fp16)
  float*  part = (float*)(ws + 64 * MB);   // 2.62 MB (2 x 32768 x 10 f32)
  ushort* W1T  = (ushort*)(ws + 96 * MB);  // 1 MB   (1024 x 512 fp16)
  ushort* W2T  = (ushort*)(ws + 97 * MB);  // 1 MB   (512 x 1024 fp16)

  transpose_f16<<<dim3(H / 32, Din / 32), 256, 0, stream>>>(W1, W1T, Din, H);
  transpose_f16<<<dim3(Hh / 32, H / 32), 256, 0, stream>>>(W2, W2T, H, Hh);

  gemm_f16_128x256<0><<<dim3(H / 256, B / 128), 256, 0, stream>>>(
      x,  W1T, b1, h1, nullptr, nullptr, H, Din);
  gemm_f16_128x256<1><<<dim3(Hh / 256, B / 128), 256, 0, stream>>>(
      h1, W2T, b2, nullptr, W3, part, Hh, H);
  finish_out<<<(B * 10 + 255) / 256, 256, 0, stream>>>(part, b3, out);
}